// Round 2
// baseline (390.545 us; speedup 1.0000x reference)
//
#include <hip/hip_runtime.h>
#include <stdint.h>

#define BATCH  2048
#define HID    512
#define CAP    65536
#define NHASH  8
#define TOPK   32
#define NSLICE 16
#define SLICE_SZ (CAP / NSLICE)   // 4096
#define ROWS_TILE 16
#define QTILES (BATCH / ROWS_TILE)  // 128
#define KTILES (CAP / ROWS_TILE)    // 4096
#define TOT_TILES (QTILES + KTILES) // 4224
#define HGRID  768                  // 3 blocks/CU persistent

typedef unsigned int   u32;
typedef unsigned long long u64;
typedef double d4 __attribute__((ext_vector_type(4)));

// ---------------------------------------------------------------------------
// K_prep: fuses three independent prologue jobs into one launch:
//   blocks 0-1 : hist16 zero + Psum[h][n] = sum_d P[n][h][d] (f64)
//   blocks 2-65: out_w transpose [o][h] -> wt [h][o]
// ---------------------------------------------------------------------------
__global__ __launch_bounds__(256) void k_prep(const float* __restrict__ proj,
                                              double* __restrict__ psumT,
                                              u32* __restrict__ hist16,
                                              const float* __restrict__ w,
                                              float* __restrict__ wt) {
    __shared__ float tile[64][65];
    int bi = blockIdx.x, tid = threadIdx.x;
    if (bi < 2) {
        int g = bi * 256 + tid;                   // 0..511
        for (int i = g; i < NSLICE * 256; i += 512) hist16[i] = 0;
        int h = g;                                // h < HID (=512) always
        for (int n = 0; n < NHASH; n++) {
            const float* p = proj + ((size_t)n * HID + h) * 16;
            double s = 0.0;
            #pragma unroll
            for (int d = 0; d < 16; d++) s += (double)p[d];
            psumT[(size_t)h * NHASH + n] = s;
        }
    } else {
        int b = bi - 2, bx = b & 7, by = b >> 3;
        int tx = tid & 63, ty = tid >> 6;
        for (int r = ty; r < 64; r += 4)
            tile[r][tx] = w[(size_t)(by * 64 + r) * HID + bx * 64 + tx];
        __syncthreads();
        for (int r = ty; r < 64; r += 4)
            wt[(size_t)(bx * 64 + r) * HID + by * 64 + tx] = tile[tx][r];
    }
}

// ---------------------------------------------------------------------------
// K_hash: persistent grid (768 blocks) striding over ALL 4224 tiles (query
// tiles 0..127, key tiles 128..4223). f64 MFMA with runtime self-calibration
// of the fragment layout (probes decode row/col/k-pairing exactly).
// Latency fixes vs prior round:
//   - 4 independent MFMA accumulator chains (8 deep each, not 32)
//   - register-prefetch of the NEXT tile issued before the MFMA phase;
//     LDS write happens after the post-scatter barrier (T14 async-stage)
// ---------------------------------------------------------------------------
__global__ __launch_bounds__(256, 3) void k_hash(const float* __restrict__ query,
                                                 const float* __restrict__ keys,
                                                 const double* __restrict__ psumT,
                                                 unsigned char* __restrict__ qhash,
                                                 unsigned char* __restrict__ khash,
                                                 u32* __restrict__ hist16) {
    __shared__ __align__(16) float sX[ROWS_TILE * HID];     // 32 KB, swizzled
    __shared__ double sAcc4[4][ROWS_TILE][8];               // 4 KB

    const int tid  = threadIdx.x;
    const int w    = tid >> 6;          // wave id -> k range [128w, 128w+128)
    const int m    = (tid & 63) & 15;   // A row / B col label
    const int kk   = (tid & 63) >> 4;   // A/B k-slot label 0..3

    // --- self-calibration probes ---
    d4 z = {0.0, 0.0, 0.0, 0.0};
    d4 pr = __builtin_amdgcn_mfma_f64_16x16x4f64((double)(m + 1), 1.0, z, 0, 0, 0);
    d4 pc = __builtin_amdgcn_mfma_f64_16x16x4f64(1.0, (double)(m + 1), z, 0, 0, 0);
    d4 pp = __builtin_amdgcn_mfma_f64_16x16x4f64((double)(1 << kk),
                                                 (double)(1 << (4 * kk)), z, 0, 0, 0);
    int rowOf[4], colOf[4];
    #pragma unroll
    for (int i = 0; i < 4; i++) {
        rowOf[i] = (int)(pr[i] * 0.25) - 1;
        colOf[i] = (int)(pc[i] * 0.25) - 1;
    }
    u32 pb = (u32)pp[0];                 // 4 set bits: e = kA + 4*kB
    u32 pairPacked = 0;                  // pairA[kB] in bits [2kB, 2kB+1]
    #pragma unroll
    for (int e = 0; e < 16; e++)
        if ((pb >> e) & 1u) pairPacked |= (u32)(e & 3) << (2 * (e >> 2));

    // B fragments, once: B-slot kk holds Psum[128w + 4j + pairA[kk]][n=m]
    const int kAdj = (int)((pairPacked >> (2 * kk)) & 3u);
    double bfrag[32];
    #pragma unroll
    for (int j = 0; j < 32; j++) {
        int kp = 128 * w + 4 * j + kAdj;
        bfrag[j] = (m < 8) ? psumT[(size_t)kp * NHASH + m] : 0.0;
    }

    const int sw = (m & 7) << 2;        // read-side swizzle for row m

    float4 pf[8];

    // prologue: stage first tile
    {
        int tt = blockIdx.x;
        const float* xb = (tt < QTILES)
            ? (query + (size_t)tt * ROWS_TILE * HID)
            : (keys + (size_t)(tt - QTILES) * ROWS_TILE * HID);
        #pragma unroll
        for (int p = 0; p < 8; p++) {
            int i = tid + 256 * p, r = i >> 7, G = i & 127;
            pf[p] = ((const float4*)(xb + (size_t)r * HID))[G];
        }
        #pragma unroll
        for (int p = 0; p < 8; p++) {
            int i = tid + 256 * p, r = i >> 7, G = i & 127;
            ((float4*)sX)[r * 128 + (G ^ (r & 7))] = pf[p];
        }
        __syncthreads();
    }

    int tt = blockIdx.x;
    for (;;) {
        const int tn = tt + HGRID;
        const bool more = (tn < TOT_TILES);

        // issue next-tile global loads NOW; they land during the MFMA phase
        if (more) {
            const float* xb = (tn < QTILES)
                ? (query + (size_t)tn * ROWS_TILE * HID)
                : (keys + (size_t)(tn - QTILES) * ROWS_TILE * HID);
            #pragma unroll
            for (int p = 0; p < 8; p++) {
                int i = tid + 256 * p, r = i >> 7, G = i & 127;
                pf[p] = ((const float4*)(xb + (size_t)r * HID))[G];
            }
        }

        // MFMA phase: 4 independent 8-deep chains (k0, k0+32, k0+64, k0+96)
        d4 ac0 = z, ac1 = z, ac2 = z, ac3 = z;
        const float* sxm = sX + m * HID;
        #pragma unroll
        for (int j8 = 0; j8 < 8; j8++) {
            int k0 = 128 * w + ((4 * j8) ^ sw) + kk;
            ac0 = __builtin_amdgcn_mfma_f64_16x16x4f64((double)sxm[k0],      bfrag[j8],      ac0, 0, 0, 0);
            ac1 = __builtin_amdgcn_mfma_f64_16x16x4f64((double)sxm[k0 + 32], bfrag[j8 + 8],  ac1, 0, 0, 0);
            ac2 = __builtin_amdgcn_mfma_f64_16x16x4f64((double)sxm[k0 + 64], bfrag[j8 + 16], ac2, 0, 0, 0);
            ac3 = __builtin_amdgcn_mfma_f64_16x16x4f64((double)sxm[k0 + 96], bfrag[j8 + 24], ac3, 0, 0, 0);
        }
        d4 acc = (ac0 + ac1) + (ac2 + ac3);

        // scatter partials by the PROBED (row,col)
        #pragma unroll
        for (int i = 0; i < 4; i++) {
            if (((unsigned)rowOf[i] < (unsigned)ROWS_TILE) && ((unsigned)colOf[i] < 8u))
                sAcc4[w][rowOf[i]][colOf[i]] = acc[i];
        }
        __syncthreads();

        // reduce current tile (16 threads) — finishes before the next barrier
        if (tid < ROWS_TILE) {
            u32 byte = 0;
            #pragma unroll
            for (int n = 0; n < 8; n++) {
                double s = sAcc4[0][tid][n] + sAcc4[1][tid][n]
                         + sAcc4[2][tid][n] + sAcc4[3][tid][n];
                if (s > 0.0) byte |= (1u << n);
            }
            if (tt < QTILES) {
                qhash[tt * ROWS_TILE + tid] = (unsigned char)byte;
            } else {
                int row = (tt - QTILES) * ROWS_TILE + tid;
                khash[row] = (unsigned char)byte;
                atomicAdd(&hist16[(row / SLICE_SZ) * 256 + byte], 1u);
            }
        }
        if (!more) break;

        // write prefetched tile into sX (safe: all MFMA reads done pre-barrier)
        #pragma unroll
        for (int p = 0; p < 8; p++) {
            int i = tid + 256 * p, r = i >> 7, G = i & 127;
            ((float4*)sX)[r * 128 + (G ^ (r & 7))] = pf[p];
        }
        __syncthreads();
        tt = tn;
    }
}

// ---------------------------------------------------------------------------
// K_scan: parallel prefix sums (shuffle-based).
// ---------------------------------------------------------------------------
__global__ __launch_bounds__(256) void k_scan(const u32* __restrict__ hist16,
                                              u32* __restrict__ bucketCnt,
                                              u32* __restrict__ bucketOff,
                                              u32* __restrict__ off16) {
    __shared__ u32 wsum[4];
    int v = threadIdx.x, lane = v & 63, wv = v >> 6;
    u32 tot = 0;
    for (int s = 0; s < NSLICE; s++) tot += hist16[s * 256 + v];
    bucketCnt[v] = tot;
    u32 inc = tot;
    #pragma unroll
    for (int s = 1; s < 64; s <<= 1) {
        u32 n = __shfl_up(inc, s, 64);
        if (lane >= s) inc += n;
    }
    if (lane == 63) wsum[wv] = inc;
    __syncthreads();
    u32 wof = 0;
    for (int i = 0; i < wv; i++) wof += wsum[i];
    u32 base = wof + inc - tot;          // exclusive prefix over buckets
    bucketOff[v] = base;
    for (int s = 0; s < NSLICE; s++) { off16[s * 256 + v] = base; base += hist16[s * 256 + v]; }
}

// ---------------------------------------------------------------------------
// K_compact: stable compaction: bucketList sorted by (hash byte, index asc).
// ---------------------------------------------------------------------------
__global__ __launch_bounds__(256) void k_compact(const unsigned char* __restrict__ khash,
                                                 const u32* __restrict__ off16,
                                                 u32* __restrict__ bucketList) {
    __shared__ unsigned char sh[SLICE_SZ];
    int s  = blockIdx.x & (NSLICE - 1);
    int bg = blockIdx.x >> 4;
    ((uint4*)sh)[threadIdx.x] = ((const uint4*)(khash + (size_t)s * SLICE_SZ))[threadIdx.x];
    __syncthreads();
    int w = threadIdx.x >> 6, lane = threadIdx.x & 63;
    int v = bg * 4 + w;
    u32 base = off16[s * 256 + v];
    for (int i = 0; i < SLICE_SZ / 64; i++) {
        int c = i * 64 + lane;
        unsigned char byte = sh[c];
        bool hit = (byte == (unsigned char)v);
        u64 m = __ballot(hit);
        if (hit) {
            int rank = __popcll(m & ((1ull << lane) - 1ull));
            bucketList[base + rank] = (u32)(s * SLICE_SZ + c);
        }
        base += (u32)__popcll(m);
    }
}

// ---------------------------------------------------------------------------
// K_attn: FUSED top-32 selection (wave 0, into LDS) + gather + scores +
// softmax + weighted V sum. Block per query.
// ---------------------------------------------------------------------------
__global__ __launch_bounds__(256) void k_attn(const float* __restrict__ keys,
                                              const float* __restrict__ vals,
                                              const float* __restrict__ query,
                                              const unsigned char* __restrict__ qhash,
                                              const u32* __restrict__ bucketCnt,
                                              const u32* __restrict__ bucketOff,
                                              const u32* __restrict__ bucketList,
                                              float* __restrict__ mo) {
    __shared__ int sIdx[TOPK];
    __shared__ float sSc[TOPK], sE[TOPK];
    __shared__ int sPos0;
    int b = blockIdx.x, tid = threadIdx.x;
    int w = tid >> 6, lane = tid & 63;

    // ---- selection: wave 0 only (per-query top-32 by (hamming dist, idx)) ----
    if (w == 0) {
        if (lane == 0) sPos0 = 0;
        u32 qh = qhash[b];

        int d[4]; u32 cnt[4], off[4];
        #pragma unroll
        for (int jj = 0; jj < 4; jj++) {
            int v = lane + jj * 64;
            d[jj] = __popc(qh ^ (u32)v);
            cnt[jj] = bucketCnt[v];
            off[jj] = bucketOff[v];
        }

        u32 ct[9];
        #pragma unroll
        for (int t = 0; t < 9; t++) {
            u32 c = 0;
            #pragma unroll
            for (int jj = 0; jj < 4; jj++) c += (d[jj] == t) ? cnt[jj] : 0u;
            #pragma unroll
            for (int s = 32; s >= 1; s >>= 1) c += __shfl_xor(c, s, 64);
            ct[t] = c;
        }

        int dcut = 0; u32 run = 0, before = 0;
        for (int t = 0; t < 9; t++) {
            before = run; run += ct[t];
            if (run >= TOPK) { dcut = t; break; }
        }
        int need = TOPK - (int)before;

        #pragma unroll
        for (int jj = 0; jj < 4; jj++) {
            if (d[jj] < dcut && cnt[jj] > 0) {
                int base = atomicAdd(&sPos0, (int)cnt[jj]);
                for (u32 e = 0; e < cnt[jj]; e++)
                    sIdx[base + e] = (int)bucketList[off[jj] + e];
            }
        }

        int nb = 0;
        #pragma unroll
        for (int jj = 0; jj < 4; jj++) nb += (d[jj] == dcut) ? 1 : 0;
        #pragma unroll
        for (int s = 32; s >= 1; s >>= 1) nb += __shfl_xor(nb, s, 64);

        if (nb == 1) {
            u32 boff = 0xFFFFFFFFu;
            #pragma unroll
            for (int jj = 0; jj < 4; jj++) if (d[jj] == dcut) boff = off[jj];
            #pragma unroll
            for (int s = 32; s >= 1; s >>= 1) boff = min(boff, __shfl_xor(boff, s, 64));
            if (lane < need)
                sIdx[(int)before + lane] = (int)bucketList[boff + lane];
        } else {
            u32 pos[4], end[4]; int val[4];
            #pragma unroll
            for (int jj = 0; jj < 4; jj++) {
                if (d[jj] == dcut && cnt[jj] > 0) {
                    pos[jj] = off[jj]; end[jj] = off[jj] + cnt[jj];
                    val[jj] = (int)bucketList[pos[jj]];
                } else { pos[jj] = 0; end[jj] = 0; val[jj] = 0x7fffffff; }
            }
            for (int it = 0; it < need; it++) {
                int m = min(min(val[0], val[1]), min(val[2], val[3]));
                int g = m;
                #pragma unroll
                for (int s = 32; s >= 1; s >>= 1) g = min(g, __shfl_xor(g, s, 64));
                if (lane == 0) sIdx[(int)before + it] = g;
                if (m == g && g != 0x7fffffff) {
                    #pragma unroll
                    for (int jj = 0; jj < 4; jj++) {
                        if (val[jj] == g) {
                            pos[jj]++;
                            val[jj] = (pos[jj] < end[jj]) ? (int)bucketList[pos[jj]] : 0x7fffffff;
                            break;
                        }
                    }
                }
            }
        }
    }
    __syncthreads();

    // ---- scores: wave w handles keys [8w, 8w+8) ----
    const float4* qp = (const float4*)(query + (size_t)b * HID + lane * 8);
    float4 qa = qp[0], qb = qp[1];

    for (int i = w * 8; i < w * 8 + 8; i++) {
        int idx = sIdx[i];
        const float4* kp = (const float4*)(keys + (size_t)idx * HID + lane * 8);
        float4 ka = kp[0], kb = kp[1];
        float dot = qa.x * ka.x + qa.y * ka.y + qa.z * ka.z + qa.w * ka.w
                  + qb.x * kb.x + qb.y * kb.y + qb.z * kb.z + qb.w * kb.w;
        #pragma unroll
        for (int s = 32; s >= 1; s >>= 1) dot += __shfl_xor(dot, s, 64);
        if (lane == 0) sSc[i] = dot * 0.04419417382415922f;  // 1/sqrt(512)
    }
    __syncthreads();

    if (tid < TOPK) {
        float m = -1e30f;
        for (int i = 0; i < TOPK; i++) m = fmaxf(m, sSc[i]);
        sE[tid] = expf(sSc[tid] - m);
    }
    __syncthreads();

    float sum = 0.f;
    for (int i = 0; i < TOPK; i++) sum += sE[i];
    float inv = 1.0f / sum;

    // ---- weighted V sum: float2 per thread (8 B/lane coalescing) ----
    int h0 = tid * 2;
    float a0 = 0.f, a1 = 0.f;
    for (int i = 0; i < TOPK; i++) {
        int idx = sIdx[i];
        float e = sE[i];
        float2 vv = *(const float2*)(vals + (size_t)idx * HID + h0);
        a0 += e * vv.x; a1 += e * vv.y;
    }
    ((float2*)(mo + (size_t)b * HID))[tid] = make_float2(a0 * inv, a1 * inv);
}

// ---------------------------------------------------------------------------
// K_proj: out[b][o] = sum_h mo[b][h] * wt[h][o] + bias[o]; 8 b-rows / block.
// ---------------------------------------------------------------------------
__global__ __launch_bounds__(256) void k_proj(const float* __restrict__ mo,
                                              const float* __restrict__ wt,
                                              const float* __restrict__ bias,
                                              float* __restrict__ out) {
    int tid = threadIdx.x;
    int o = (blockIdx.x & 1) * 256 + tid;
    int bb = (blockIdx.x >> 1) * 8;
    float acc[8];
    #pragma unroll
    for (int r = 0; r < 8; r++) acc[r] = 0.f;
    for (int h = 0; h < HID; h++) {
        float wv = wt[(size_t)h * HID + o];
        #pragma unroll
        for (int r = 0; r < 8; r++)
            acc[r] += mo[(size_t)(bb + r) * HID + h] * wv;
    }
    float bv = bias[o];
    #pragma unroll
    for (int r = 0; r < 8; r++)
        out[(size_t)(bb + r) * HID + o] = acc[r] + bv;
}

// ---------------------------------------------------------------------------
extern "C" void kernel_launch(void* const* d_in, const int* in_sizes, int n_in,
                              void* d_out, int out_size, void* d_ws, size_t ws_size,
                              hipStream_t stream) {
    const float* query = (const float*)d_in[0];
    const float* keys  = (const float*)d_in[1];
    const float* vals  = (const float*)d_in[2];
    const float* proj  = (const float*)d_in[3];
    const float* outw  = (const float*)d_in[4];
    const float* outbp = (const float*)d_in[5];
    float* out = (float*)d_out;

    char* ws = (char*)d_ws;
    double*        psumT      = (double*)(ws + 0);              // 32 KB
    unsigned char* qhash      = (unsigned char*)(ws + 32768);   // 2 KB
    unsigned char* khash      = (unsigned char*)(ws + 34816);   // 64 KB
    u32*           hist16     = (u32*)(ws + 100352);            // 16 KB
    u32*           bucketCnt  = (u32*)(ws + 116736);            // 1 KB
    u32*           bucketOff  = (u32*)(ws + 117760);            // 1 KB
    u32*           off16      = (u32*)(ws + 118784);            // 16 KB
    u32*           bucketList = (u32*)(ws + 135168);            // 256 KB
    float*         mo         = (float*)(ws + 397312);          // 4 MB
    float*         wt         = (float*)(ws + 4591616);         // 1 MB
    (void)in_sizes; (void)n_in; (void)out_size; (void)ws_size;

    k_prep<<<66, 256, 0, stream>>>(proj, psumT, hist16, outw, wt);
    k_hash<<<HGRID, 256, 0, stream>>>(query, keys, psumT, qhash, khash, hist16);
    k_scan<<<1, 256, 0, stream>>>(hist16, bucketCnt, bucketOff, off16);
    k_compact<<<1024, 256, 0, stream>>>(khash, off16, bucketList);
    k_attn<<<BATCH, 256, 0, stream>>>(keys, vals, query, qhash, bucketCnt, bucketOff, bucketList, mo);
    k_proj<<<512, 256, 0, stream>>>(mo, wt, outbp, out);
}

// Round 3
// 357.686 us; speedup vs baseline: 1.0919x; 1.0919x over previous
//
#include <hip/hip_runtime.h>
#include <stdint.h>

#define BATCH  2048
#define HID    512
#define CAP    65536
#define NHASH  8
#define TOPK   32
#define NSLICE 16
#define SLICE_SZ (CAP / NSLICE)   // 4096
#define ROWS_TILE 16
#define QTILES (BATCH / ROWS_TILE)  // 128
#define KTILES (CAP / ROWS_TILE)    // 4096
#define TOT_TILES (QTILES + KTILES) // 4224
#define HGRID  512                  // 2 blocks/CU persistent (68 KB LDS each)

typedef unsigned int   u32;
typedef unsigned long long u64;
typedef double d4 __attribute__((ext_vector_type(4)));

// ---------------------------------------------------------------------------
// K_prep: fuses three independent prologue jobs into one launch:
//   blocks 0-1 : hist16 zero + Psum[h][n] = sum_d P[n][h][d] (f64)
//   blocks 2-65: out_w transpose [o][h] -> wt [h][o]
// ---------------------------------------------------------------------------
__global__ __launch_bounds__(256) void k_prep(const float* __restrict__ proj,
                                              double* __restrict__ psumT,
                                              u32* __restrict__ hist16,
                                              const float* __restrict__ w,
                                              float* __restrict__ wt) {
    __shared__ float tile[64][65];
    int bi = blockIdx.x, tid = threadIdx.x;
    if (bi < 2) {
        int g = bi * 256 + tid;                   // 0..511
        for (int i = g; i < NSLICE * 256; i += 512) hist16[i] = 0;
        int h = g;                                // h < HID (=512) always
        for (int n = 0; n < NHASH; n++) {
            const float* p = proj + ((size_t)n * HID + h) * 16;
            double s = 0.0;
            #pragma unroll
            for (int d = 0; d < 16; d++) s += (double)p[d];
            psumT[(size_t)h * NHASH + n] = s;
        }
    } else {
        int b = bi - 2, bx = b & 7, by = b >> 3;
        int tx = tid & 63, ty = tid >> 6;
        for (int r = ty; r < 64; r += 4)
            tile[r][tx] = w[(size_t)(by * 64 + r) * HID + bx * 64 + tx];
        __syncthreads();
        for (int r = ty; r < 64; r += 4)
            wt[(size_t)(bx * 64 + r) * HID + by * 64 + tx] = tile[tx][r];
    }
}

// ---------------------------------------------------------------------------
// Async global->LDS staging of one 16x512 tile (32 KB). LDS destination is
// LINEAR (hardware requirement: wave-uniform base + lane*16); the swizzle
// lives on the GLOBAL source address (involution G ^ (r&7)), so the read
// side's  k ^ ((m&7)<<2)  indexing is unchanged. Zero VGPR cost.
// ---------------------------------------------------------------------------
__device__ __forceinline__ void stage_tile(const float* __restrict__ xb,
                                           float* buf, int tid) {
    #pragma unroll
    for (int p = 0; p < 8; p++) {
        int i = p * 256 + tid;
        int r = i >> 7;
        int G = (i & 127) ^ (r & 7);
        const float4* g = (const float4*)(xb + (size_t)r * HID) + G;
        float4* l = ((float4*)buf) + i;
        __builtin_amdgcn_global_load_lds(
            (const __attribute__((address_space(1))) void*)g,
            (__attribute__((address_space(3))) void*)l, 16, 0, 0);
    }
}

// ---------------------------------------------------------------------------
// K_hash: persistent grid (512 blocks, 2/CU) striding over ALL 4224 tiles
// (query tiles 0..127, key tiles 128..4223). f64 MFMA with runtime
// self-calibration of the fragment layout.
// Pipeline (replaces R2's scratch-spilling register prefetch):
//   - double-buffered LDS, global_load_lds async staging (no VGPR round-trip)
//   - raw s_barrier + counted s_waitcnt vmcnt(8): next tile's 8 loads stay
//     in flight across the barrier while MFMA runs on the current tile
//     (__syncthreads would drain vmcnt(0) and serialize the pipeline)
//   - 4 independent 8-deep MFMA chains (not one 32-deep serial chain)
// ---------------------------------------------------------------------------
__global__ __launch_bounds__(256, 2) void k_hash(const float* __restrict__ query,
                                                 const float* __restrict__ keys,
                                                 const double* __restrict__ psumT,
                                                 unsigned char* __restrict__ qhash,
                                                 unsigned char* __restrict__ khash,
                                                 u32* __restrict__ hist16) {
    __shared__ __align__(16) float sX0[ROWS_TILE * HID];    // 32 KB
    __shared__ __align__(16) float sX1[ROWS_TILE * HID];    // 32 KB
    __shared__ double sAcc4[4][ROWS_TILE][8];               // 4 KB

    const int tid  = threadIdx.x;
    const int w    = tid >> 6;          // wave id -> k range [128w, 128w+128)
    const int m    = (tid & 63) & 15;   // A row / B col label
    const int kk   = (tid & 63) >> 4;   // A/B k-slot label 0..3

    // prologue: stage first tile immediately (hide under setup)
    {
        int t0 = blockIdx.x;
        const float* xb = (t0 < QTILES)
            ? (query + (size_t)t0 * ROWS_TILE * HID)
            : (keys + (size_t)(t0 - QTILES) * ROWS_TILE * HID);
        stage_tile(xb, sX0, tid);
    }

    // --- self-calibration probes ---
    d4 z = {0.0, 0.0, 0.0, 0.0};
    d4 pr = __builtin_amdgcn_mfma_f64_16x16x4f64((double)(m + 1), 1.0, z, 0, 0, 0);
    d4 pc = __builtin_amdgcn_mfma_f64_16x16x4f64(1.0, (double)(m + 1), z, 0, 0, 0);
    d4 pp = __builtin_amdgcn_mfma_f64_16x16x4f64((double)(1 << kk),
                                                 (double)(1 << (4 * kk)), z, 0, 0, 0);
    int rowOf[4], colOf[4];
    #pragma unroll
    for (int i = 0; i < 4; i++) {
        rowOf[i] = (int)(pr[i] * 0.25) - 1;
        colOf[i] = (int)(pc[i] * 0.25) - 1;
    }
    u32 pb = (u32)pp[0];                 // 4 set bits: e = kA + 4*kB
    u32 pairPacked = 0;                  // pairA[kB] in bits [2kB, 2kB+1]
    #pragma unroll
    for (int e = 0; e < 16; e++)
        if ((pb >> e) & 1u) pairPacked |= (u32)(e & 3) << (2 * (e >> 2));

    // B fragments, once: B-slot kk holds Psum[128w + 4j + pairA[kk]][n=m]
    const int kAdj = (int)((pairPacked >> (2 * kk)) & 3u);
    double bfrag[32];
    #pragma unroll
    for (int j = 0; j < 32; j++) {
        int kp = 128 * w + 4 * j + kAdj;
        bfrag[j] = (m < 8) ? psumT[(size_t)kp * NHASH + m] : 0.0;
    }

    const int sw = (m & 7) << 2;        // read-side swizzle for row m

    float* rbuf = sX0;                  // buffer being computed on
    float* wbuf = sX1;                  // buffer being staged

    int tt = blockIdx.x;
    for (;;) {
        const int tn = tt + HGRID;
        const bool more = (tn < TOT_TILES);

        // issue next-tile async loads into wbuf; they fly during MFMA
        if (more) {
            const float* xb = (tn < QTILES)
                ? (query + (size_t)tn * ROWS_TILE * HID)
                : (keys + (size_t)(tn - QTILES) * ROWS_TILE * HID);
            stage_tile(xb, wbuf, tid);
            // wait for rbuf's 8 loads only; wbuf's 8 stay in flight
            asm volatile("s_waitcnt vmcnt(8)" ::: "memory");
        } else {
            asm volatile("s_waitcnt vmcnt(0)" ::: "memory");
        }
        __builtin_amdgcn_s_barrier();
        __builtin_amdgcn_sched_barrier(0);

        // MFMA phase: 4 independent 8-deep chains (k0, k0+32, k0+64, k0+96)
        d4 ac0 = z, ac1 = z, ac2 = z, ac3 = z;
        const float* sxm = rbuf + m * HID;
        #pragma unroll
        for (int j8 = 0; j8 < 8; j8++) {
            int k0 = 128 * w + ((4 * j8) ^ sw) + kk;
            ac0 = __builtin_amdgcn_mfma_f64_16x16x4f64((double)sxm[k0],      bfrag[j8],      ac0, 0, 0, 0);
            ac1 = __builtin_amdgcn_mfma_f64_16x16x4f64((double)sxm[k0 + 32], bfrag[j8 + 8],  ac1, 0, 0, 0);
            ac2 = __builtin_amdgcn_mfma_f64_16x16x4f64((double)sxm[k0 + 64], bfrag[j8 + 16], ac2, 0, 0, 0);
            ac3 = __builtin_amdgcn_mfma_f64_16x16x4f64((double)sxm[k0 + 96], bfrag[j8 + 24], ac3, 0, 0, 0);
        }
        d4 acc = (ac0 + ac1) + (ac2 + ac3);

        // scatter partials by the PROBED (row,col)
        #pragma unroll
        for (int i = 0; i < 4; i++) {
            if (((unsigned)rowOf[i] < (unsigned)ROWS_TILE) && ((unsigned)colOf[i] < 8u))
                sAcc4[w][rowOf[i]][colOf[i]] = acc[i];
        }
        // LDS-only drain barrier: vmem (wbuf prefetch) stays in flight
        asm volatile("s_waitcnt lgkmcnt(0)" ::: "memory");
        __builtin_amdgcn_s_barrier();
        __builtin_amdgcn_sched_barrier(0);

        // reduce current tile (16 threads)
        if (tid < ROWS_TILE) {
            u32 byte = 0;
            #pragma unroll
            for (int n = 0; n < 8; n++) {
                double s = sAcc4[0][tid][n] + sAcc4[1][tid][n]
                         + sAcc4[2][tid][n] + sAcc4[3][tid][n];
                if (s > 0.0) byte |= (1u << n);
            }
            if (tt < QTILES) {
                qhash[tt * ROWS_TILE + tid] = (unsigned char)byte;
            } else {
                int row = (tt - QTILES) * ROWS_TILE + tid;
                khash[row] = (unsigned char)byte;
                atomicAdd(&hist16[(row / SLICE_SZ) * 256 + byte], 1u);
            }
        }
        if (!more) break;

        // swap: computed buffer becomes next staging target (its reads are
        // done — all waves passed the post-scatter barrier)
        float* t = rbuf; rbuf = wbuf; wbuf = t;
        tt = tn;
    }
}

// ---------------------------------------------------------------------------
// K_scan: parallel prefix sums (shuffle-based).
// ---------------------------------------------------------------------------
__global__ __launch_bounds__(256) void k_scan(const u32* __restrict__ hist16,
                                              u32* __restrict__ bucketCnt,
                                              u32* __restrict__ bucketOff,
                                              u32* __restrict__ off16) {
    __shared__ u32 wsum[4];
    int v = threadIdx.x, lane = v & 63, wv = v >> 6;
    u32 tot = 0;
    for (int s = 0; s < NSLICE; s++) tot += hist16[s * 256 + v];
    bucketCnt[v] = tot;
    u32 inc = tot;
    #pragma unroll
    for (int s = 1; s < 64; s <<= 1) {
        u32 n = __shfl_up(inc, s, 64);
        if (lane >= s) inc += n;
    }
    if (lane == 63) wsum[wv] = inc;
    __syncthreads();
    u32 wof = 0;
    for (int i = 0; i < wv; i++) wof += wsum[i];
    u32 base = wof + inc - tot;          // exclusive prefix over buckets
    bucketOff[v] = base;
    for (int s = 0; s < NSLICE; s++) { off16[s * 256 + v] = base; base += hist16[s * 256 + v]; }
}

// ---------------------------------------------------------------------------
// K_compact: stable compaction: bucketList sorted by (hash byte, index asc).
// ---------------------------------------------------------------------------
__global__ __launch_bounds__(256) void k_compact(const unsigned char* __restrict__ khash,
                                                 const u32* __restrict__ off16,
                                                 u32* __restrict__ bucketList) {
    __shared__ unsigned char sh[SLICE_SZ];
    int s  = blockIdx.x & (NSLICE - 1);
    int bg = blockIdx.x >> 4;
    ((uint4*)sh)[threadIdx.x] = ((const uint4*)(khash + (size_t)s * SLICE_SZ))[threadIdx.x];
    __syncthreads();
    int w = threadIdx.x >> 6, lane = threadIdx.x & 63;
    int v = bg * 4 + w;
    u32 base = off16[s * 256 + v];
    for (int i = 0; i < SLICE_SZ / 64; i++) {
        int c = i * 64 + lane;
        unsigned char byte = sh[c];
        bool hit = (byte == (unsigned char)v);
        u64 m = __ballot(hit);
        if (hit) {
            int rank = __popcll(m & ((1ull << lane) - 1ull));
            bucketList[base + rank] = (u32)(s * SLICE_SZ + c);
        }
        base += (u32)__popcll(m);
    }
}

// ---------------------------------------------------------------------------
// K_attn: FUSED top-32 selection (wave 0, into LDS) + gather + scores +
// softmax + weighted V sum. Block per query.
// ---------------------------------------------------------------------------
__global__ __launch_bounds__(256) void k_attn(const float* __restrict__ keys,
                                              const float* __restrict__ vals,
                                              const float* __restrict__ query,
                                              const unsigned char* __restrict__ qhash,
                                              const u32* __restrict__ bucketCnt,
                                              const u32* __restrict__ bucketOff,
                                              const u32* __restrict__ bucketList,
                                              float* __restrict__ mo) {
    __shared__ int sIdx[TOPK];
    __shared__ float sSc[TOPK], sE[TOPK];
    __shared__ int sPos0;
    int b = blockIdx.x, tid = threadIdx.x;
    int w = tid >> 6, lane = tid & 63;

    // ---- selection: wave 0 only (per-query top-32 by (hamming dist, idx)) ----
    if (w == 0) {
        if (lane == 0) sPos0 = 0;
        u32 qh = qhash[b];

        int d[4]; u32 cnt[4], off[4];
        #pragma unroll
        for (int jj = 0; jj < 4; jj++) {
            int v = lane + jj * 64;
            d[jj] = __popc(qh ^ (u32)v);
            cnt[jj] = bucketCnt[v];
            off[jj] = bucketOff[v];
        }

        u32 ct[9];
        #pragma unroll
        for (int t = 0; t < 9; t++) {
            u32 c = 0;
            #pragma unroll
            for (int jj = 0; jj < 4; jj++) c += (d[jj] == t) ? cnt[jj] : 0u;
            #pragma unroll
            for (int s = 32; s >= 1; s >>= 1) c += __shfl_xor(c, s, 64);
            ct[t] = c;
        }

        int dcut = 0; u32 run = 0, before = 0;
        for (int t = 0; t < 9; t++) {
            before = run; run += ct[t];
            if (run >= TOPK) { dcut = t; break; }
        }
        int need = TOPK - (int)before;

        #pragma unroll
        for (int jj = 0; jj < 4; jj++) {
            if (d[jj] < dcut && cnt[jj] > 0) {
                int base = atomicAdd(&sPos0, (int)cnt[jj]);
                for (u32 e = 0; e < cnt[jj]; e++)
                    sIdx[base + e] = (int)bucketList[off[jj] + e];
            }
        }

        int nb = 0;
        #pragma unroll
        for (int jj = 0; jj < 4; jj++) nb += (d[jj] == dcut) ? 1 : 0;
        #pragma unroll
        for (int s = 32; s >= 1; s >>= 1) nb += __shfl_xor(nb, s, 64);

        if (nb == 1) {
            u32 boff = 0xFFFFFFFFu;
            #pragma unroll
            for (int jj = 0; jj < 4; jj++) if (d[jj] == dcut) boff = off[jj];
            #pragma unroll
            for (int s = 32; s >= 1; s >>= 1) boff = min(boff, __shfl_xor(boff, s, 64));
            if (lane < need)
                sIdx[(int)before + lane] = (int)bucketList[boff + lane];
        } else {
            u32 pos[4], end[4]; int val[4];
            #pragma unroll
            for (int jj = 0; jj < 4; jj++) {
                if (d[jj] == dcut && cnt[jj] > 0) {
                    pos[jj] = off[jj]; end[jj] = off[jj] + cnt[jj];
                    val[jj] = (int)bucketList[pos[jj]];
                } else { pos[jj] = 0; end[jj] = 0; val[jj] = 0x7fffffff; }
            }
            for (int it = 0; it < need; it++) {
                int m = min(min(val[0], val[1]), min(val[2], val[3]));
                int g = m;
                #pragma unroll
                for (int s = 32; s >= 1; s >>= 1) g = min(g, __shfl_xor(g, s, 64));
                if (lane == 0) sIdx[(int)before + it] = g;
                if (m == g && g != 0x7fffffff) {
                    #pragma unroll
                    for (int jj = 0; jj < 4; jj++) {
                        if (val[jj] == g) {
                            pos[jj]++;
                            val[jj] = (pos[jj] < end[jj]) ? (int)bucketList[pos[jj]] : 0x7fffffff;
                            break;
                        }
                    }
                }
            }
        }
    }
    __syncthreads();

    // ---- scores: wave w handles keys [8w, 8w+8) ----
    const float4* qp = (const float4*)(query + (size_t)b * HID + lane * 8);
    float4 qa = qp[0], qb = qp[1];

    for (int i = w * 8; i < w * 8 + 8; i++) {
        int idx = sIdx[i];
        const float4* kp = (const float4*)(keys + (size_t)idx * HID + lane * 8);
        float4 ka = kp[0], kb = kp[1];
        float dot = qa.x * ka.x + qa.y * ka.y + qa.z * ka.z + qa.w * ka.w
                  + qb.x * kb.x + qb.y * kb.y + qb.z * kb.z + qb.w * kb.w;
        #pragma unroll
        for (int s = 32; s >= 1; s >>= 1) dot += __shfl_xor(dot, s, 64);
        if (lane == 0) sSc[i] = dot * 0.04419417382415922f;  // 1/sqrt(512)
    }
    __syncthreads();

    if (tid < TOPK) {
        float m = -1e30f;
        for (int i = 0; i < TOPK; i++) m = fmaxf(m, sSc[i]);
        sE[tid] = expf(sSc[tid] - m);
    }
    __syncthreads();

    float sum = 0.f;
    for (int i = 0; i < TOPK; i++) sum += sE[i];
    float inv = 1.0f / sum;

    // ---- weighted V sum: float2 per thread (8 B/lane coalescing) ----
    int h0 = tid * 2;
    float a0 = 0.f, a1 = 0.f;
    for (int i = 0; i < TOPK; i++) {
        int idx = sIdx[i];
        float e = sE[i];
        float2 vv = *(const float2*)(vals + (size_t)idx * HID + h0);
        a0 += e * vv.x; a1 += e * vv.y;
    }
    ((float2*)(mo + (size_t)b * HID))[tid] = make_float2(a0 * inv, a1 * inv);
}

// ---------------------------------------------------------------------------
// K_proj: out[b][o] = sum_h mo[b][h] * wt[h][o] + bias[o]; 8 b-rows / block.
// ---------------------------------------------------------------------------
__global__ __launch_bounds__(256) void k_proj(const float* __restrict__ mo,
                                              const float* __restrict__ wt,
                                              const float* __restrict__ bias,
                                              float* __restrict__ out) {
    int tid = threadIdx.x;
    int o = (blockIdx.x & 1) * 256 + tid;
    int bb = (blockIdx.x >> 1) * 8;
    float acc[8];
    #pragma unroll
    for (int r = 0; r < 8; r++) acc[r] = 0.f;
    for (int h = 0; h < HID; h++) {
        float wv = wt[(size_t)h * HID + o];
        #pragma unroll
        for (int r = 0; r < 8; r++)
            acc[r] += mo[(size_t)(bb + r) * HID + h] * wv;
    }
    float bv = bias[o];
    #pragma unroll
    for (int r = 0; r < 8; r++)
        out[(size_t)(bb + r) * HID + o] = acc[r] + bv;
}

// ---------------------------------------------------------------------------
extern "C" void kernel_launch(void* const* d_in, const int* in_sizes, int n_in,
                              void* d_out, int out_size, void* d_ws, size_t ws_size,
                              hipStream_t stream) {
    const float* query = (const float*)d_in[0];
    const float* keys  = (const float*)d_in[1];
    const float* vals  = (const float*)d_in[2];
    const float* proj  = (const float*)d_in[3];
    const float* outw  = (const float*)d_in[4];
    const float* outbp = (const float*)d_in[5];
    float* out = (float*)d_out;

    char* ws = (char*)d_ws;
    double*        psumT      = (double*)(ws + 0);              // 32 KB
    unsigned char* qhash      = (unsigned char*)(ws + 32768);   // 2 KB
    unsigned char* khash      = (unsigned char*)(ws + 34816);   // 64 KB
    u32*           hist16     = (u32*)(ws + 100352);            // 16 KB
    u32*           bucketCnt  = (u32*)(ws + 116736);            // 1 KB
    u32*           bucketOff  = (u32*)(ws + 117760);            // 1 KB
    u32*           off16      = (u32*)(ws + 118784);            // 16 KB
    u32*           bucketList = (u32*)(ws + 135168);            // 256 KB
    float*         mo         = (float*)(ws + 397312);          // 4 MB
    float*         wt         = (float*)(ws + 4591616);         // 1 MB
    (void)in_sizes; (void)n_in; (void)out_size; (void)ws_size;

    k_prep<<<66, 256, 0, stream>>>(proj, psumT, hist16, outw, wt);
    k_hash<<<HGRID, 256, 0, stream>>>(query, keys, psumT, qhash, khash, hist16);
    k_scan<<<1, 256, 0, stream>>>(hist16, bucketCnt, bucketOff, off16);
    k_compact<<<1024, 256, 0, stream>>>(khash, off16, bucketList);
    k_attn<<<BATCH, 256, 0, stream>>>(keys, vals, query, qhash, bucketCnt, bucketOff, bucketList, mo);
    k_proj<<<512, 256, 0, stream>>>(mo, wt, outbp, out);
}